// Round 18
// baseline (178.336 us; speedup 1.0000x reference)
//
#include <hip/hip_runtime.h>
#include <hip/hip_bf16.h>

#define NU 50000
#define NI 30000
#define NN 80000     // NU + NI
#define KDIM 64
#define DD0 768
#define DD1 128
#define DD 896       // DD0 + DD1 = 14 chunks of 64

#define BROWS 128            // dst rows per bucket
#define NB (NN / BROWS)      // 625 buckets
#define CAPB 5120            // entries per bucket region
#define CAP 96               // uniform ELL capacity per row (u16 slots)
#define REGION_BYTES 24576   // per-bucket region
#define ENTS_STRIDE (REGION_BYTES / 4)
#define CHUNK_PAIRS 4096

typedef __attribute__((ext_vector_type(8))) short short8v;
typedef __attribute__((ext_vector_type(4))) short short4v;
typedef __attribute__((ext_vector_type(4))) float float4v;
typedef unsigned short ushort_t;

struct bf16pair { short hi, lo; };

__device__ inline bf16pair f32_split_bf16(float v) {
    __hip_bfloat16 h = __float2bfloat16(v);
    float hf = __bfloat162float(h);
    __hip_bfloat16 l = __float2bfloat16(v - hf);
    bf16pair p;
    p.hi = *reinterpret_cast<short*>(&h);
    p.lo = *reinterpret_cast<short*>(&l);
    return p;
}

__device__ inline float bf16bits_to_f32(ushort_t u) {
    return __uint_as_float(((unsigned int)u) << 16);
}

__device__ inline ushort_t f32_to_bf16_rne(float f) {
    unsigned int u = __float_as_uint(f);
    unsigned int r = (u + 0x7FFFu + ((u >> 16) & 1u)) >> 16;
    return (ushort_t)r;
}

// ---------------------------------------------------------------------------
// W -> transposed bf16 hi/lo:  WTh/WTl[col][k]
// ---------------------------------------------------------------------------
__global__ void wtcvt_kernel(const float* __restrict__ W,
                             short* __restrict__ WTh, short* __restrict__ WTl)
{
    const int i = blockIdx.x * 256 + threadIdx.x;   // over DD*KDIM
    if (i < DD * KDIM) {
        const int k = i >> 6, col = i & 63;
        const bf16pair p = f32_split_bf16(W[i]);
        WTh[col * DD + k] = p.hi;
        WTl[col * DD + k] = p.lo;
    }
}

// ---------------------------------------------------------------------------
// 1) proj via bf16x2-split MFMA — R14/R17 proven structure (64-row tile,
// 4 waves, LDS staging) upgraded to a 2-DEEP register prefetch: two
// statically-named load sets (A/B, chunk loop unrolled by 2 — no register
// rotation, which R13 showed the compiler collapses). Loads for chunk c+2
// are issued at iter c and consumed (LDS write) at iter c+2, so they stay
// in flight across two MFMA phases + 4 barriers (~2x the latency cover of
// the 1-deep pipeline that ran at 56 us / 1.0 TB/s).
// Writes f32 item rows into Fp, bf16 dinv-scaled rows into curS.
// ---------------------------------------------------------------------------
__global__ __launch_bounds__(256) void proj_kernel(
    const float* __restrict__ F0, const float* __restrict__ F1,
    const short* __restrict__ WTh, const short* __restrict__ WTl,
    const float* __restrict__ b, const float* __restrict__ dinv,
    float* __restrict__ Fp, ushort_t* __restrict__ curS)
{
    __shared__ short Ah[64][72];
    __shared__ short Al[64][72];
    __shared__ short Bh[64][72];
    __shared__ short Bl[64][72];

    const int tid  = threadIdx.x;
    const int wv   = tid >> 6;      // wave 0..3
    const int lane = tid & 63;
    const int lr   = lane & 15;     // frag row/col
    const int grp  = lane >> 4;     // frag k-group
    const int rowBase = blockIdx.x * 64;

    // per-thread staging indices (constant across chunks)
    const int aR[4] = { (0*256+tid) >> 4, (1*256+tid) >> 4,
                        (2*256+tid) >> 4, (3*256+tid) >> 4 };
    const int aK    = (tid & 15) * 4;
    const int bCol[2] = { (0*256+tid) >> 3, (1*256+tid) >> 3 };
    const int bK      = (tid & 7) * 8;

    float4   pA0[4], pA1[4];
    short8v  pBh0[2], pBl0[2], pBh1[2], pBl1[2];

    auto loadChunk = [&](int c, float4 (&qA)[4],
                         short8v (&qBh)[2], short8v (&qBl)[2]) {
        #pragma unroll
        for (int rep = 0; rep < 4; ++rep) {
            const int r = rowBase + aR[rep];
            float4 v = make_float4(0.f, 0.f, 0.f, 0.f);
            if (r < NI) {
                if (c < 12)
                    v = *(const float4*)&F0[(size_t)r * DD0 + c * 64 + aK];
                else
                    v = *(const float4*)&F1[(size_t)r * DD1 + (c - 12) * 64 + aK];
            }
            qA[rep] = v;
        }
        #pragma unroll
        for (int rep = 0; rep < 2; ++rep) {
            qBh[rep] = *(const short8v*)&WTh[(size_t)bCol[rep] * DD + c * 64 + bK];
            qBl[rep] = *(const short8v*)&WTl[(size_t)bCol[rep] * DD + c * 64 + bK];
        }
    };

    float4v acc[4] = {};            // 4 n-tiles of 16x16, 4 f32 each

    auto step = [&](int c, float4 (&qA)[4],
                    short8v (&qBh)[2], short8v (&qBl)[2]) {
        // ---- regs -> LDS (A converted to bf16 hi/lo)
        #pragma unroll
        for (int rep = 0; rep < 4; ++rep) {
            const float4 v = qA[rep];
            const bf16pair p0 = f32_split_bf16(v.x);
            const bf16pair p1 = f32_split_bf16(v.y);
            const bf16pair p2 = f32_split_bf16(v.z);
            const bf16pair p3 = f32_split_bf16(v.w);
            short4v h4, l4;
            h4[0] = p0.hi; h4[1] = p1.hi; h4[2] = p2.hi; h4[3] = p3.hi;
            l4[0] = p0.lo; l4[1] = p1.lo; l4[2] = p2.lo; l4[3] = p3.lo;
            *(short4v*)&Ah[aR[rep]][aK] = h4;
            *(short4v*)&Al[aR[rep]][aK] = l4;
        }
        #pragma unroll
        for (int rep = 0; rep < 2; ++rep) {
            *(short8v*)&Bh[bCol[rep]][bK] = qBh[rep];
            *(short8v*)&Bl[bCol[rep]][bK] = qBl[rep];
        }
        if (c + 2 < 14) loadChunk(c + 2, qA, qBh, qBl);  // 2-deep prefetch
        __syncthreads();

        // ---- MFMA: 2 k-steps x 4 n-tiles x 3 hi/lo combos
        #pragma unroll
        for (int ks = 0; ks < 2; ++ks) {
            const int ko = ks * 32 + grp * 8;
            const short8v ah = *(const short8v*)&Ah[wv * 16 + lr][ko];
            const short8v al = *(const short8v*)&Al[wv * 16 + lr][ko];
            #pragma unroll
            for (int nt = 0; nt < 4; ++nt) {
                const short8v bh = *(const short8v*)&Bh[nt * 16 + lr][ko];
                const short8v bl = *(const short8v*)&Bl[nt * 16 + lr][ko];
                acc[nt] = __builtin_amdgcn_mfma_f32_16x16x32_bf16(ah, bh, acc[nt], 0, 0, 0);
                acc[nt] = __builtin_amdgcn_mfma_f32_16x16x32_bf16(ah, bl, acc[nt], 0, 0, 0);
                acc[nt] = __builtin_amdgcn_mfma_f32_16x16x32_bf16(al, bh, acc[nt], 0, 0, 0);
            }
        }
        __syncthreads();
    };

    loadChunk(0, pA0, pBh0, pBl0);
    loadChunk(1, pA1, pBh1, pBl1);
    #pragma unroll
    for (int c = 0; c < 14; c += 2) {
        step(c,     pA0, pBh0, pBl0);
        step(c + 1, pA1, pBh1, pBl1);
    }

    // ---- epilogue: lane holds D[row = 4*grp + i][col = nt*16 + lr]
    float bias[4];
    #pragma unroll
    for (int nt = 0; nt < 4; ++nt) bias[nt] = b[nt * 16 + lr];

    float y[4][4];
    float ssp[4];
    #pragma unroll
    for (int i = 0; i < 4; ++i) {
        ssp[i] = 0.f;
        #pragma unroll
        for (int nt = 0; nt < 4; ++nt) {
            y[nt][i] = acc[nt][i] + bias[nt];
            ssp[i] += y[nt][i] * y[nt][i];
        }
    }
    #pragma unroll
    for (int i = 0; i < 4; ++i) {
        float ss = ssp[i];
        ss += __shfl_xor(ss, 1);
        ss += __shfl_xor(ss, 2);
        ss += __shfl_xor(ss, 4);
        ss += __shfl_xor(ss, 8);
        const int r = rowBase + wv * 16 + 4 * grp + i;
        if (r < NI) {
            const float inv = 1.0f / fmaxf(sqrtf(ss), 1e-12f);
            const float dv  = dinv[NU + r];
            #pragma unroll
            for (int nt = 0; nt < 4; ++nt) {
                const float o = y[nt][i] * inv;
                Fp[(size_t)(NU + r) * KDIM + nt * 16 + lr] = o;
                curS[(size_t)(NU + r) * KDIM + nt * 16 + lr] = f32_to_bf16_rne(o * dv);
            }
        }
    }
}

// user rows: curS = bf16(Gu * dinv[row])
__global__ void userinit_kernel(const float* __restrict__ Gu,
                                const float* __restrict__ dinv,
                                ushort_t* __restrict__ curS)
{
    const int i = blockIdx.x * blockDim.x + threadIdx.x;  // float4 index
    if (i < NU * KDIM / 4) {
        const int row = i >> 4;
        const float dv = dinv[row];
        const float4 g = ((const float4*)Gu)[i];
        short4v s;
        s[0] = (short)f32_to_bf16_rne(g.x * dv);
        s[1] = (short)f32_to_bf16_rne(g.y * dv);
        s[2] = (short)f32_to_bf16_rne(g.z * dv);
        s[3] = (short)f32_to_bf16_rne(g.w * dv);
        *(short4v*)&curS[(size_t)i * 4] = s;
    }
}

// ---------------------------------------------------------------------------
// Partition: bucket 2M directed entries by dst>>7 (R7-proven).
// ---------------------------------------------------------------------------
__global__ __launch_bounds__(256) void part_kernel(
    const int* __restrict__ src, const int* __restrict__ dst,
    int* __restrict__ bcur, unsigned int* __restrict__ ents, int E2)
{
    __shared__ int bcntL[NB];
    __shared__ int bposL[NB];
    const int tid = threadIdx.x;
    const int pairBase = blockIdx.x * CHUNK_PAIRS;

    for (int i = tid; i < NB; i += 256) bcntL[i] = 0;
    __syncthreads();

    #pragma unroll
    for (int it = 0; it < CHUNK_PAIRS / 256; ++it) {
        const int p = pairBase + it * 256 + tid;
        if (p < E2) {
            const int u  = src[p];
            const int iF = dst[p];
            atomicAdd(&bcntL[iF >> 7], 1);
            atomicAdd(&bcntL[u  >> 7], 1);
        }
    }
    __syncthreads();

    for (int bkt = tid; bkt < NB; bkt += 256) {
        const int c = bcntL[bkt];
        bposL[bkt] = (c > 0) ? atomicAdd(&bcur[bkt], c) : 0;
        bcntL[bkt] = 0;
    }
    __syncthreads();

    #pragma unroll
    for (int it = 0; it < CHUNK_PAIRS / 256; ++it) {
        const int p = pairBase + it * 256 + tid;
        if (p < E2) {
            const int u  = src[p];
            const int iF = dst[p];
            {
                const int bkt = iF >> 7;
                const int k = bposL[bkt] + atomicAdd(&bcntL[bkt], 1);
                if (k < CAPB)
                    ents[(size_t)bkt * ENTS_STRIDE + k] =
                        ((unsigned int)(iF & 127) << 16) | (unsigned int)u;
            }
            {
                const int bkt = u >> 7;
                const int k = bposL[bkt] + atomicAdd(&bcntL[bkt], 1);
                if (k < CAPB)
                    ents[(size_t)bkt * ENTS_STRIDE + k] =
                        ((unsigned int)(u & 127) << 16) | (unsigned int)(iF - NU);
            }
        }
    }
}

// ---------------------------------------------------------------------------
// toELL: stage bucket entries in LDS, place into u16 ELL [row][CAP]; emits
// cnt + dinv. (ELL aliases the entry region; LDS staging makes that safe.)
// ---------------------------------------------------------------------------
__global__ __launch_bounds__(256) void toELL_kernel(
    const int* __restrict__ bcur, unsigned int* __restrict__ ents,
    ushort_t* __restrict__ col,
    int* __restrict__ cnt, float* __restrict__ dinv)
{
    __shared__ unsigned int eL[CAPB];
    __shared__ int curL[BROWS];
    const int bkt = blockIdx.x;
    const int tid = threadIdx.x;

    int n = bcur[bkt]; n = (n < CAPB) ? n : CAPB;
    const unsigned int* ep = ents + (size_t)bkt * ENTS_STRIDE;

    for (int j = tid; j < n; j += 256) eL[j] = ep[j];
    if (tid < BROWS) curL[tid] = 0;
    __syncthreads();

    const size_t rowB = (size_t)bkt * BROWS;
    for (int j = tid; j < n; j += 256) {
        const unsigned int e = eL[j];
        const int dl = (int)(e >> 16);
        const int slot = atomicAdd(&curL[dl], 1);
        if (slot < CAP)
            col[(rowB + dl) * CAP + slot] = (ushort_t)(e & 0xFFFFu);
    }
    __syncthreads();

    if (tid < BROWS) {
        int c = curL[tid];
        c = (c < CAP) ? c : CAP;
        const size_t row = rowB + tid;
        cnt[row]  = c;
        dinv[row] = (c > 0) ? rsqrtf((float)c) : 0.0f;
    }
}

// ---------------------------------------------------------------------------
// 3) pull, two-rows-per-wave dword gathers: lanes 0-31 own row0, 32-63 own
// row1; each lane gathers one uint32 (2 bf16) of its row per edge — gather
// instructions per edge HALVE vs the per-lane-ushort form, with the same 8
// outstanding loads (16 edges in flight). Col reads stay scalar (uniform
// uint4 from both rows, cndmask select). No cross-lane combines.
//    nxtS[row] = bf16( dinv^2 * sum_j curS[col_j] ).
// ---------------------------------------------------------------------------
__global__ __launch_bounds__(256) void pull_kernel(
    const ushort_t* __restrict__ curS, ushort_t* __restrict__ nxtS,
    const int* __restrict__ cnt,
    const ushort_t* __restrict__ col,
    const float* __restrict__ dinv,
    int rowStart, int nPairs)
{
    const int pr = __builtin_amdgcn_readfirstlane(
        (int)((blockIdx.x * blockDim.x + threadIdx.x) >> 6));
    const int lane = threadIdx.x & 63;
    const int sub  = lane & 31;     // dword index within the 128 B row
    const int h    = lane >> 5;     // which row of the pair
    if (pr >= nPairs) return;
    const int row0 = rowStart + pr * 2;
    const int rowH = row0 + h;
    const int addB = (row0 < NU) ? NU : 0;   // uniform within phase
    const int n0 = cnt[row0];
    const int n1 = cnt[row0 + 1];
    const int nH   = h ? n1 : n0;
    const int nMin = (n0 < n1) ? n0 : n1;
    const int nMax = (n0 < n1) ? n1 : n0;
    const unsigned int* cp0 = (const unsigned int*)(col + (size_t)row0 * CAP);
    const unsigned int* cp1 = (const unsigned int*)(col + ((size_t)row0 + 1) * CAP);

    float aLo0 = 0.f, aLo1 = 0.f, aHi0 = 0.f, aHi1 = 0.f;
    int j = 0;
    for (; j + 8 <= nMin; j += 8) {
        const uint4 D0 = *(const uint4*)(cp0 + (j >> 1));
        const uint4 D1 = *(const uint4*)(cp1 + (j >> 1));
        const unsigned int dx = h ? D1.x : D0.x;
        const unsigned int dy = h ? D1.y : D0.y;
        const unsigned int dz = h ? D1.z : D0.z;
        const unsigned int dw = h ? D1.w : D0.w;
        const int c0 = (int)(dx & 0xFFFFu) + addB;
        const int c1 = (int)(dx >> 16)     + addB;
        const int c2 = (int)(dy & 0xFFFFu) + addB;
        const int c3 = (int)(dy >> 16)     + addB;
        const int c4 = (int)(dz & 0xFFFFu) + addB;
        const int c5 = (int)(dz >> 16)     + addB;
        const int c6 = (int)(dw & 0xFFFFu) + addB;
        const int c7 = (int)(dw >> 16)     + addB;
        const unsigned int v0 = *(const unsigned int*)&curS[((size_t)c0 << 6) + sub * 2];
        const unsigned int v1 = *(const unsigned int*)&curS[((size_t)c1 << 6) + sub * 2];
        const unsigned int v2 = *(const unsigned int*)&curS[((size_t)c2 << 6) + sub * 2];
        const unsigned int v3 = *(const unsigned int*)&curS[((size_t)c3 << 6) + sub * 2];
        const unsigned int v4 = *(const unsigned int*)&curS[((size_t)c4 << 6) + sub * 2];
        const unsigned int v5 = *(const unsigned int*)&curS[((size_t)c5 << 6) + sub * 2];
        const unsigned int v6 = *(const unsigned int*)&curS[((size_t)c6 << 6) + sub * 2];
        const unsigned int v7 = *(const unsigned int*)&curS[((size_t)c7 << 6) + sub * 2];
        aLo0 += __uint_as_float(v0 << 16) + __uint_as_float(v2 << 16);
        aLo1 += __uint_as_float(v1 << 16) + __uint_as_float(v3 << 16);
        aHi0 += __uint_as_float(v0 & 0xFFFF0000u) + __uint_as_float(v2 & 0xFFFF0000u);
        aHi1 += __uint_as_float(v1 & 0xFFFF0000u) + __uint_as_float(v3 & 0xFFFF0000u);
        aLo0 += __uint_as_float(v4 << 16) + __uint_as_float(v6 << 16);
        aLo1 += __uint_as_float(v5 << 16) + __uint_as_float(v7 << 16);
        aHi0 += __uint_as_float(v4 & 0xFFFF0000u) + __uint_as_float(v6 & 0xFFFF0000u);
        aHi1 += __uint_as_float(v5 & 0xFFFF0000u) + __uint_as_float(v7 & 0xFFFF0000u);
    }
    for (; j < nMax; j += 2) {       // tail: per-half predication
        const unsigned int d0 = cp0[j >> 1];
        const unsigned int d1 = cp1[j >> 1];
        const unsigned int d  = h ? d1 : d0;
        if (j < nH) {
            const int c = (int)(d & 0xFFFFu) + addB;
            const unsigned int v = *(const unsigned int*)&curS[((size_t)c << 6) + sub * 2];
            aLo0 += __uint_as_float(v << 16);
            aHi0 += __uint_as_float(v & 0xFFFF0000u);
        }
        if (j + 1 < nH) {
            const int c = (int)(d >> 16) + addB;
            const unsigned int v = *(const unsigned int*)&curS[((size_t)c << 6) + sub * 2];
            aLo1 += __uint_as_float(v << 16);
            aHi1 += __uint_as_float(v & 0xFFFF0000u);
        }
    }

    const float dv = dinv[rowH];
    const float f = dv * dv;
    const unsigned int w = (unsigned int)f32_to_bf16_rne((aLo0 + aLo1) * f)
                         | ((unsigned int)f32_to_bf16_rne((aHi0 + aHi1) * f) << 16);
    ((unsigned int*)&nxtS[(size_t)rowH << 6])[sub] = w;
}

// ---------------------------------------------------------------------------
// 4) out: acc_r = x0_r + (S1_r + S2_r)/dinv_r + dinv_r * sum_j S2[col_j(r)]
//    xui[b] = (1/16) * dot(acc_u, acc_i).  Layer-3 evaluated only here.
// ---------------------------------------------------------------------------
__device__ inline float row_acc(int row, float x0, int lane,
                                const ushort_t* __restrict__ S1,
                                const ushort_t* __restrict__ S2,
                                const int* __restrict__ cnt,
                                const ushort_t* __restrict__ col,
                                const float* __restrict__ dinv)
{
    const float dv  = dinv[row];
    const float rdv = (dv > 0.f) ? 1.0f / dv : 0.0f;
    const float s1 = bf16bits_to_f32(S1[((size_t)row << 6) + lane]);
    const float s2 = bf16bits_to_f32(S2[((size_t)row << 6) + lane]);

    const unsigned int* cpd = (const unsigned int*)(col + (size_t)row * CAP);
    const int addB = (row < NU) ? NU : 0;
    const int n = cnt[row];
    float a0 = 0.f, a1 = 0.f, a2 = 0.f, a3 = 0.f;
    int j = 0;
    for (; j + 8 <= n; j += 8) {
        const uint4 cc = *(const uint4*)(cpd + (j >> 1));
        const int c0 = (int)(cc.x & 0xFFFFu) + addB;
        const int c1 = (int)(cc.x >> 16)     + addB;
        const int c2 = (int)(cc.y & 0xFFFFu) + addB;
        const int c3 = (int)(cc.y >> 16)     + addB;
        const int c4 = (int)(cc.z & 0xFFFFu) + addB;
        const int c5 = (int)(cc.z >> 16)     + addB;
        const int c6 = (int)(cc.w & 0xFFFFu) + addB;
        const int c7 = (int)(cc.w >> 16)     + addB;
        const float v0 = bf16bits_to_f32(S2[((size_t)c0 << 6) + lane]);
        const float v1 = bf16bits_to_f32(S2[((size_t)c1 << 6) + lane]);
        const float v2 = bf16bits_to_f32(S2[((size_t)c2 << 6) + lane]);
        const float v3 = bf16bits_to_f32(S2[((size_t)c3 << 6) + lane]);
        const float v4 = bf16bits_to_f32(S2[((size_t)c4 << 6) + lane]);
        const float v5 = bf16bits_to_f32(S2[((size_t)c5 << 6) + lane]);
        const float v6 = bf16bits_to_f32(S2[((size_t)c6 << 6) + lane]);
        const float v7 = bf16bits_to_f32(S2[((size_t)c7 << 6) + lane]);
        a0 += v0 + v4; a1 += v1 + v5; a2 += v2 + v6; a3 += v3 + v7;
    }
    for (; j < n; ++j) {
        const unsigned int d = cpd[j >> 1];
        const int c = (int)((j & 1) ? (d >> 16) : (d & 0xFFFFu)) + addB;
        a0 += bf16bits_to_f32(S2[((size_t)c << 6) + lane]);
    }

    return x0 + (s1 + s2) * rdv + dv * ((a0 + a1) + (a2 + a3));
}

__global__ __launch_bounds__(256) void out_kernel(
    const float* __restrict__ Gu, const float* __restrict__ Fp,
    const ushort_t* __restrict__ S1, const ushort_t* __restrict__ S2,
    const int* __restrict__ cnt, const ushort_t* __restrict__ col,
    const float* __restrict__ dinv,
    const int* __restrict__ uidx, const int* __restrict__ iidx,
    float* __restrict__ out, int B)
{
    const int wid = __builtin_amdgcn_readfirstlane(
        (int)((blockIdx.x * blockDim.x + threadIdx.x) >> 6));
    const int lane = threadIdx.x & 63;
    if (wid >= B) return;
    const int u  = uidx[wid];
    const int rI = NU + iidx[wid];

    const float au = row_acc(u,  Gu[((size_t)u  << 6) + lane], lane,
                             S1, S2, cnt, col, dinv);
    const float ai = row_acc(rI, Fp[((size_t)rI << 6) + lane], lane,
                             S1, S2, cnt, col, dinv);
    float p = au * ai;
    #pragma unroll
    for (int m = 32; m >= 1; m >>= 1) p += __shfl_xor(p, m);
    if (lane == 0) out[wid] = p * (1.0f / 16.0f);
}

extern "C" void kernel_launch(void* const* d_in, const int* in_sizes, int n_in,
                              void* d_out, int out_size, void* d_ws, size_t ws_size,
                              hipStream_t stream)
{
    const float* Gu = (const float*)d_in[0];
    const float* F0 = (const float*)d_in[1];
    const float* F1 = (const float*)d_in[2];
    const float* W  = (const float*)d_in[3];
    const float* pb = (const float*)d_in[4];
    const int* edge = (const int*)d_in[5];
    const int* uidx = (const int*)d_in[6];
    const int* iidx = (const int*)d_in[7];
    const int E  = in_sizes[5] / 2;      // 2,000,000 directed edges
    const int E2 = E / 2;                // 1,000,000 mirrored pairs
    const int B = in_sizes[6];           // 4096
    const int* srcp = edge;              // first E2: user ids
    const int* dstp = edge + E;          // first E2: item ids (+NU)

    const size_t XE = (size_t)NN * KDIM;
    float*    Fp    = (float*)d_ws;                        // XE f32 (items)
    ushort_t* curA  = (ushort_t*)(Fp + XE);                // XE bf16
    ushort_t* curB  = curA + XE;                           // XE bf16
    float*    dinv  = (float*)(curB + XE);                 // NN
    int*      cnt   = (int*)(dinv + NN);                   // NN
    int*      bcur  = cnt + NN;                            // NB
    short*    WTh   = (short*)(bcur + NB);                 // 64*896
    short*    WTl   = WTh + (size_t)KDIM * DD;             // 64*896
    ushort_t* col   = (ushort_t*)(WTl + (size_t)KDIM * DD);
    unsigned int* ents = (unsigned int*)col;               // aliased region

    // build: partition -> bucket-local ELL (emits cnt, dinv)
    (void)hipMemsetAsync(bcur, 0, NB * sizeof(int), stream);
    part_kernel<<<(E2 + CHUNK_PAIRS - 1) / CHUNK_PAIRS, 256, 0, stream>>>(
        srcp, dstp, bcur, ents, E2);
    toELL_kernel<<<NB, 256, 0, stream>>>(bcur, ents, col, cnt, dinv);

    // W -> transposed bf16 hi/lo
    wtcvt_kernel<<<(DD * KDIM + 255) / 256, 256, 0, stream>>>(W, WTh, WTl);

    // S0: curA = bf16(dinv .* x0)  (x0 = [Gu; Fproj]; Fp keeps item x0 in f32)
    userinit_kernel<<<(NU * KDIM / 4 + 255) / 256, 256, 0, stream>>>(
        Gu, dinv, curA);
    proj_kernel<<<(NI + 63) / 64, 256, 0, stream>>>(F0, F1, WTh, WTl, pb,
                                                    dinv, Fp, curA);

    // layers 1-2 (phase-split, 2 rows per wave); S1 = curB, S2 = curA
    const int gridU = (NU / 2 * 64 + 255) / 256;   // 6250
    const int gridI = (NI / 2 * 64 + 255) / 256;   // 3750
    pull_kernel<<<gridU, 256, 0, stream>>>(curA, curB, cnt, col, dinv, 0,  NU / 2);
    pull_kernel<<<gridI, 256, 0, stream>>>(curA, curB, cnt, col, dinv, NU, NI / 2);
    pull_kernel<<<gridU, 256, 0, stream>>>(curB, curA, cnt, col, dinv, 0,  NU / 2);
    pull_kernel<<<gridI, 256, 0, stream>>>(curB, curA, cnt, col, dinv, NU, NI / 2);

    // out: layer-3 at sampled rows only + mean + dot
    out_kernel<<<(int)(((size_t)B * 64 + 255) / 256), 256, 0, stream>>>(
        Gu, Fp, curB, curA, cnt, col, dinv, uidx, iidx, (float*)d_out, B);
}

// Round 19
// 177.306 us; speedup vs baseline: 1.0058x; 1.0058x over previous
//
#include <hip/hip_runtime.h>
#include <hip/hip_bf16.h>

#define NU 50000
#define NI 30000
#define NN 80000     // NU + NI
#define KDIM 64
#define DD0 768
#define DD1 128
#define DD 896       // DD0 + DD1 = 14 chunks of 64

#define BROWS 128            // dst rows per bucket
#define NB (NN / BROWS)      // 625 buckets
#define CAPB 5120            // entries per bucket region
#define CAP 96               // uniform ELL capacity per row (u16 slots)
#define REGION_BYTES 24576   // per-bucket region
#define ENTS_STRIDE (REGION_BYTES / 4)
#define CHUNK_PAIRS 4096

typedef __attribute__((ext_vector_type(8))) short short8v;
typedef __attribute__((ext_vector_type(4))) short short4v;
typedef __attribute__((ext_vector_type(4))) float float4v;
typedef unsigned short ushort_t;

struct bf16pair { short hi, lo; };

__device__ inline bf16pair f32_split_bf16(float v) {
    __hip_bfloat16 h = __float2bfloat16(v);
    float hf = __bfloat162float(h);
    __hip_bfloat16 l = __float2bfloat16(v - hf);
    bf16pair p;
    p.hi = *reinterpret_cast<short*>(&h);
    p.lo = *reinterpret_cast<short*>(&l);
    return p;
}

__device__ inline float bf16bits_to_f32(ushort_t u) {
    return __uint_as_float(((unsigned int)u) << 16);
}

__device__ inline ushort_t f32_to_bf16_rne(float f) {
    unsigned int u = __float_as_uint(f);
    unsigned int r = (u + 0x7FFFu + ((u >> 16) & 1u)) >> 16;
    return (ushort_t)r;
}

// ---------------------------------------------------------------------------
// W -> transposed bf16 hi/lo:  WTh/WTl[col][k]
// ---------------------------------------------------------------------------
__global__ void wtcvt_kernel(const float* __restrict__ W,
                             short* __restrict__ WTh, short* __restrict__ WTl)
{
    const int i = blockIdx.x * 256 + threadIdx.x;   // over DD*KDIM
    if (i < DD * KDIM) {
        const int k = i >> 6, col = i & 63;
        const bf16pair p = f32_split_bf16(W[i]);
        WTh[col * DD + k] = p.hi;
        WTl[col * DD + k] = p.lo;
    }
}

// ---------------------------------------------------------------------------
// 1) proj via bf16x2-split MFMA — R14/R17 PROVEN best (56 us, VGPR 56):
// 64-row tile, 4 waves, LDS staging, 1-deep register prefetch. Disproven
// alternatives: 16-row (R11), LDS-free (R12), reg-dbuf (R13), 32-row (R15),
// split-K (R16), 2-deep prefetch (R18: VGPR 92, 72 us — the compiler's
// vmcnt(0) drain at each barrier voids deeper pipelines).
// Writes f32 item rows into Fp, bf16 dinv-scaled rows into curS.
// ---------------------------------------------------------------------------
__global__ __launch_bounds__(256) void proj_kernel(
    const float* __restrict__ F0, const float* __restrict__ F1,
    const short* __restrict__ WTh, const short* __restrict__ WTl,
    const float* __restrict__ b, const float* __restrict__ dinv,
    float* __restrict__ Fp, ushort_t* __restrict__ curS)
{
    __shared__ short Ah[64][72];
    __shared__ short Al[64][72];
    __shared__ short Bh[64][72];
    __shared__ short Bl[64][72];

    const int tid  = threadIdx.x;
    const int wv   = tid >> 6;      // wave 0..3
    const int lane = tid & 63;
    const int lr   = lane & 15;     // frag row/col
    const int grp  = lane >> 4;     // frag k-group
    const int rowBase = blockIdx.x * 64;

    // per-thread staging indices (constant across chunks)
    const int aR[4] = { (0*256+tid) >> 4, (1*256+tid) >> 4,
                        (2*256+tid) >> 4, (3*256+tid) >> 4 };
    const int aK    = (tid & 15) * 4;
    const int bCol[2] = { (0*256+tid) >> 3, (1*256+tid) >> 3 };
    const int bK      = (tid & 7) * 8;

    float4   pA[4];
    short8v  pBh[2], pBl[2];

    auto loadChunk = [&](int c) {
        #pragma unroll
        for (int rep = 0; rep < 4; ++rep) {
            const int r = rowBase + aR[rep];
            float4 v = make_float4(0.f, 0.f, 0.f, 0.f);
            if (r < NI) {
                if (c < 12)
                    v = *(const float4*)&F0[(size_t)r * DD0 + c * 64 + aK];
                else
                    v = *(const float4*)&F1[(size_t)r * DD1 + (c - 12) * 64 + aK];
            }
            pA[rep] = v;
        }
        #pragma unroll
        for (int rep = 0; rep < 2; ++rep) {
            pBh[rep] = *(const short8v*)&WTh[(size_t)bCol[rep] * DD + c * 64 + bK];
            pBl[rep] = *(const short8v*)&WTl[(size_t)bCol[rep] * DD + c * 64 + bK];
        }
    };

    float4v acc[4] = {};            // 4 n-tiles of 16x16, 4 f32 each

    loadChunk(0);
    for (int c = 0; c < 14; ++c) {
        // ---- regs -> LDS (A converted to bf16 hi/lo)
        #pragma unroll
        for (int rep = 0; rep < 4; ++rep) {
            const float4 v = pA[rep];
            const bf16pair p0 = f32_split_bf16(v.x);
            const bf16pair p1 = f32_split_bf16(v.y);
            const bf16pair p2 = f32_split_bf16(v.z);
            const bf16pair p3 = f32_split_bf16(v.w);
            short4v h4, l4;
            h4[0] = p0.hi; h4[1] = p1.hi; h4[2] = p2.hi; h4[3] = p3.hi;
            l4[0] = p0.lo; l4[1] = p1.lo; l4[2] = p2.lo; l4[3] = p3.lo;
            *(short4v*)&Ah[aR[rep]][aK] = h4;
            *(short4v*)&Al[aR[rep]][aK] = l4;
        }
        #pragma unroll
        for (int rep = 0; rep < 2; ++rep) {
            *(short8v*)&Bh[bCol[rep]][bK] = pBh[rep];
            *(short8v*)&Bl[bCol[rep]][bK] = pBl[rep];
        }
        if (c < 13) loadChunk(c + 1);   // in flight across MFMA phase
        __syncthreads();

        // ---- MFMA: 2 k-steps x 4 n-tiles x 3 hi/lo combos
        #pragma unroll
        for (int ks = 0; ks < 2; ++ks) {
            const int ko = ks * 32 + grp * 8;
            const short8v ah = *(const short8v*)&Ah[wv * 16 + lr][ko];
            const short8v al = *(const short8v*)&Al[wv * 16 + lr][ko];
            #pragma unroll
            for (int nt = 0; nt < 4; ++nt) {
                const short8v bh = *(const short8v*)&Bh[nt * 16 + lr][ko];
                const short8v bl = *(const short8v*)&Bl[nt * 16 + lr][ko];
                acc[nt] = __builtin_amdgcn_mfma_f32_16x16x32_bf16(ah, bh, acc[nt], 0, 0, 0);
                acc[nt] = __builtin_amdgcn_mfma_f32_16x16x32_bf16(ah, bl, acc[nt], 0, 0, 0);
                acc[nt] = __builtin_amdgcn_mfma_f32_16x16x32_bf16(al, bh, acc[nt], 0, 0, 0);
            }
        }
        __syncthreads();
    }

    // ---- epilogue: lane holds D[row = 4*grp + i][col = nt*16 + lr]
    float bias[4];
    #pragma unroll
    for (int nt = 0; nt < 4; ++nt) bias[nt] = b[nt * 16 + lr];

    float y[4][4];
    float ssp[4];
    #pragma unroll
    for (int i = 0; i < 4; ++i) {
        ssp[i] = 0.f;
        #pragma unroll
        for (int nt = 0; nt < 4; ++nt) {
            y[nt][i] = acc[nt][i] + bias[nt];
            ssp[i] += y[nt][i] * y[nt][i];
        }
    }
    #pragma unroll
    for (int i = 0; i < 4; ++i) {
        float ss = ssp[i];
        ss += __shfl_xor(ss, 1);
        ss += __shfl_xor(ss, 2);
        ss += __shfl_xor(ss, 4);
        ss += __shfl_xor(ss, 8);
        const int r = rowBase + wv * 16 + 4 * grp + i;
        if (r < NI) {
            const float inv = 1.0f / fmaxf(sqrtf(ss), 1e-12f);
            const float dv  = dinv[NU + r];
            #pragma unroll
            for (int nt = 0; nt < 4; ++nt) {
                const float o = y[nt][i] * inv;
                Fp[(size_t)(NU + r) * KDIM + nt * 16 + lr] = o;
                curS[(size_t)(NU + r) * KDIM + nt * 16 + lr] = f32_to_bf16_rne(o * dv);
            }
        }
    }
}

// user rows: curS = bf16(Gu * dinv[row])
__global__ void userinit_kernel(const float* __restrict__ Gu,
                                const float* __restrict__ dinv,
                                ushort_t* __restrict__ curS)
{
    const int i = blockIdx.x * blockDim.x + threadIdx.x;  // float4 index
    if (i < NU * KDIM / 4) {
        const int row = i >> 4;
        const float dv = dinv[row];
        const float4 g = ((const float4*)Gu)[i];
        short4v s;
        s[0] = (short)f32_to_bf16_rne(g.x * dv);
        s[1] = (short)f32_to_bf16_rne(g.y * dv);
        s[2] = (short)f32_to_bf16_rne(g.z * dv);
        s[3] = (short)f32_to_bf16_rne(g.w * dv);
        *(short4v*)&curS[(size_t)i * 4] = s;
    }
}

// ---------------------------------------------------------------------------
// Partition: bucket 2M directed entries by dst>>7 (R7-proven).
// ---------------------------------------------------------------------------
__global__ __launch_bounds__(256) void part_kernel(
    const int* __restrict__ src, const int* __restrict__ dst,
    int* __restrict__ bcur, unsigned int* __restrict__ ents, int E2)
{
    __shared__ int bcntL[NB];
    __shared__ int bposL[NB];
    const int tid = threadIdx.x;
    const int pairBase = blockIdx.x * CHUNK_PAIRS;

    for (int i = tid; i < NB; i += 256) bcntL[i] = 0;
    __syncthreads();

    #pragma unroll
    for (int it = 0; it < CHUNK_PAIRS / 256; ++it) {
        const int p = pairBase + it * 256 + tid;
        if (p < E2) {
            const int u  = src[p];
            const int iF = dst[p];
            atomicAdd(&bcntL[iF >> 7], 1);
            atomicAdd(&bcntL[u  >> 7], 1);
        }
    }
    __syncthreads();

    for (int bkt = tid; bkt < NB; bkt += 256) {
        const int c = bcntL[bkt];
        bposL[bkt] = (c > 0) ? atomicAdd(&bcur[bkt], c) : 0;
        bcntL[bkt] = 0;
    }
    __syncthreads();

    #pragma unroll
    for (int it = 0; it < CHUNK_PAIRS / 256; ++it) {
        const int p = pairBase + it * 256 + tid;
        if (p < E2) {
            const int u  = src[p];
            const int iF = dst[p];
            {
                const int bkt = iF >> 7;
                const int k = bposL[bkt] + atomicAdd(&bcntL[bkt], 1);
                if (k < CAPB)
                    ents[(size_t)bkt * ENTS_STRIDE + k] =
                        ((unsigned int)(iF & 127) << 16) | (unsigned int)u;
            }
            {
                const int bkt = u >> 7;
                const int k = bposL[bkt] + atomicAdd(&bcntL[bkt], 1);
                if (k < CAPB)
                    ents[(size_t)bkt * ENTS_STRIDE + k] =
                        ((unsigned int)(u & 127) << 16) | (unsigned int)(iF - NU);
            }
        }
    }
}

// ---------------------------------------------------------------------------
// toELL: stage bucket entries in LDS, place into u16 ELL [row][CAP]; emits
// cnt + dinv. (ELL aliases the entry region; LDS staging makes that safe.)
// ---------------------------------------------------------------------------
__global__ __launch_bounds__(256) void toELL_kernel(
    const int* __restrict__ bcur, unsigned int* __restrict__ ents,
    ushort_t* __restrict__ col,
    int* __restrict__ cnt, float* __restrict__ dinv)
{
    __shared__ unsigned int eL[CAPB];
    __shared__ int curL[BROWS];
    const int bkt = blockIdx.x;
    const int tid = threadIdx.x;

    int n = bcur[bkt]; n = (n < CAPB) ? n : CAPB;
    const unsigned int* ep = ents + (size_t)bkt * ENTS_STRIDE;

    for (int j = tid; j < n; j += 256) eL[j] = ep[j];
    if (tid < BROWS) curL[tid] = 0;
    __syncthreads();

    const size_t rowB = (size_t)bkt * BROWS;
    for (int j = tid; j < n; j += 256) {
        const unsigned int e = eL[j];
        const int dl = (int)(e >> 16);
        const int slot = atomicAdd(&curL[dl], 1);
        if (slot < CAP)
            col[(rowB + dl) * CAP + slot] = (ushort_t)(e & 0xFFFFu);
    }
    __syncthreads();

    if (tid < BROWS) {
        int c = curL[tid];
        c = (c < CAP) ? c : CAP;
        const size_t row = rowB + tid;
        cnt[row]  = c;
        dinv[row] = (c > 0) ? rsqrtf((float)c) : 0.0f;
    }
}

// ---------------------------------------------------------------------------
// 3) pull, two-rows-per-wave dword gathers (R18-proven, ~16 us aggregate
// win): lanes 0-31 own row0, 32-63 own row1; each lane gathers one uint32
// (2 bf16) of its row per edge. Col reads scalar; no cross-lane combines.
//    nxtS[row] = bf16( dinv^2 * sum_j curS[col_j] ).
// ---------------------------------------------------------------------------
__global__ __launch_bounds__(256) void pull_kernel(
    const ushort_t* __restrict__ curS, ushort_t* __restrict__ nxtS,
    const int* __restrict__ cnt,
    const ushort_t* __restrict__ col,
    const float* __restrict__ dinv,
    int rowStart, int nPairs)
{
    const int pr = __builtin_amdgcn_readfirstlane(
        (int)((blockIdx.x * blockDim.x + threadIdx.x) >> 6));
    const int lane = threadIdx.x & 63;
    const int sub  = lane & 31;     // dword index within the 128 B row
    const int h    = lane >> 5;     // which row of the pair
    if (pr >= nPairs) return;
    const int row0 = rowStart + pr * 2;
    const int rowH = row0 + h;
    const int addB = (row0 < NU) ? NU : 0;   // uniform within phase
    const int n0 = cnt[row0];
    const int n1 = cnt[row0 + 1];
    const int nH   = h ? n1 : n0;
    const int nMin = (n0 < n1) ? n0 : n1;
    const int nMax = (n0 < n1) ? n1 : n0;
    const unsigned int* cp0 = (const unsigned int*)(col + (size_t)row0 * CAP);
    const unsigned int* cp1 = (const unsigned int*)(col + ((size_t)row0 + 1) * CAP);

    float aLo0 = 0.f, aLo1 = 0.f, aHi0 = 0.f, aHi1 = 0.f;
    int j = 0;
    for (; j + 8 <= nMin; j += 8) {
        const uint4 D0 = *(const uint4*)(cp0 + (j >> 1));
        const uint4 D1 = *(const uint4*)(cp1 + (j >> 1));
        const unsigned int dx = h ? D1.x : D0.x;
        const unsigned int dy = h ? D1.y : D0.y;
        const unsigned int dz = h ? D1.z : D0.z;
        const unsigned int dw = h ? D1.w : D0.w;
        const int c0 = (int)(dx & 0xFFFFu) + addB;
        const int c1 = (int)(dx >> 16)     + addB;
        const int c2 = (int)(dy & 0xFFFFu) + addB;
        const int c3 = (int)(dy >> 16)     + addB;
        const int c4 = (int)(dz & 0xFFFFu) + addB;
        const int c5 = (int)(dz >> 16)     + addB;
        const int c6 = (int)(dw & 0xFFFFu) + addB;
        const int c7 = (int)(dw >> 16)     + addB;
        const unsigned int v0 = *(const unsigned int*)&curS[((size_t)c0 << 6) + sub * 2];
        const unsigned int v1 = *(const unsigned int*)&curS[((size_t)c1 << 6) + sub * 2];
        const unsigned int v2 = *(const unsigned int*)&curS[((size_t)c2 << 6) + sub * 2];
        const unsigned int v3 = *(const unsigned int*)&curS[((size_t)c3 << 6) + sub * 2];
        const unsigned int v4 = *(const unsigned int*)&curS[((size_t)c4 << 6) + sub * 2];
        const unsigned int v5 = *(const unsigned int*)&curS[((size_t)c5 << 6) + sub * 2];
        const unsigned int v6 = *(const unsigned int*)&curS[((size_t)c6 << 6) + sub * 2];
        const unsigned int v7 = *(const unsigned int*)&curS[((size_t)c7 << 6) + sub * 2];
        aLo0 += __uint_as_float(v0 << 16) + __uint_as_float(v2 << 16);
        aLo1 += __uint_as_float(v1 << 16) + __uint_as_float(v3 << 16);
        aHi0 += __uint_as_float(v0 & 0xFFFF0000u) + __uint_as_float(v2 & 0xFFFF0000u);
        aHi1 += __uint_as_float(v1 & 0xFFFF0000u) + __uint_as_float(v3 & 0xFFFF0000u);
        aLo0 += __uint_as_float(v4 << 16) + __uint_as_float(v6 << 16);
        aLo1 += __uint_as_float(v5 << 16) + __uint_as_float(v7 << 16);
        aHi0 += __uint_as_float(v4 & 0xFFFF0000u) + __uint_as_float(v6 & 0xFFFF0000u);
        aHi1 += __uint_as_float(v5 & 0xFFFF0000u) + __uint_as_float(v7 & 0xFFFF0000u);
    }
    for (; j < nMax; j += 2) {       // tail: per-half predication
        const unsigned int d0 = cp0[j >> 1];
        const unsigned int d1 = cp1[j >> 1];
        const unsigned int d  = h ? d1 : d0;
        if (j < nH) {
            const int c = (int)(d & 0xFFFFu) + addB;
            const unsigned int v = *(const unsigned int*)&curS[((size_t)c << 6) + sub * 2];
            aLo0 += __uint_as_float(v << 16);
            aHi0 += __uint_as_float(v & 0xFFFF0000u);
        }
        if (j + 1 < nH) {
            const int c = (int)(d >> 16) + addB;
            const unsigned int v = *(const unsigned int*)&curS[((size_t)c << 6) + sub * 2];
            aLo1 += __uint_as_float(v << 16);
            aHi1 += __uint_as_float(v & 0xFFFF0000u);
        }
    }

    const float dv = dinv[rowH];
    const float f = dv * dv;
    const unsigned int w = (unsigned int)f32_to_bf16_rne((aLo0 + aLo1) * f)
                         | ((unsigned int)f32_to_bf16_rne((aHi0 + aHi1) * f) << 16);
    ((unsigned int*)&nxtS[(size_t)rowH << 6])[sub] = w;
}

// ---------------------------------------------------------------------------
// 4) out: acc_r = x0_r + (S1_r + S2_r)/dinv_r + dinv_r * sum_j S2[col_j(r)]
//    xui[b] = (1/16) * dot(acc_u, acc_i).  Layer-3 evaluated only here.
// ---------------------------------------------------------------------------
__device__ inline float row_acc(int row, float x0, int lane,
                                const ushort_t* __restrict__ S1,
                                const ushort_t* __restrict__ S2,
                                const int* __restrict__ cnt,
                                const ushort_t* __restrict__ col,
                                const float* __restrict__ dinv)
{
    const float dv  = dinv[row];
    const float rdv = (dv > 0.f) ? 1.0f / dv : 0.0f;
    const float s1 = bf16bits_to_f32(S1[((size_t)row << 6) + lane]);
    const float s2 = bf16bits_to_f32(S2[((size_t)row << 6) + lane]);

    const unsigned int* cpd = (const unsigned int*)(col + (size_t)row * CAP);
    const int addB = (row < NU) ? NU : 0;
    const int n = cnt[row];
    float a0 = 0.f, a1 = 0.f, a2 = 0.f, a3 = 0.f;
    int j = 0;
    for (; j + 8 <= n; j += 8) {
        const uint4 cc = *(const uint4*)(cpd + (j >> 1));
        const int c0 = (int)(cc.x & 0xFFFFu) + addB;
        const int c1 = (int)(cc.x >> 16)     + addB;
        const int c2 = (int)(cc.y & 0xFFFFu) + addB;
        const int c3 = (int)(cc.y >> 16)     + addB;
        const int c4 = (int)(cc.z & 0xFFFFu) + addB;
        const int c5 = (int)(cc.z >> 16)     + addB;
        const int c6 = (int)(cc.w & 0xFFFFu) + addB;
        const int c7 = (int)(cc.w >> 16)     + addB;
        const float v0 = bf16bits_to_f32(S2[((size_t)c0 << 6) + lane]);
        const float v1 = bf16bits_to_f32(S2[((size_t)c1 << 6) + lane]);
        const float v2 = bf16bits_to_f32(S2[((size_t)c2 << 6) + lane]);
        const float v3 = bf16bits_to_f32(S2[((size_t)c3 << 6) + lane]);
        const float v4 = bf16bits_to_f32(S2[((size_t)c4 << 6) + lane]);
        const float v5 = bf16bits_to_f32(S2[((size_t)c5 << 6) + lane]);
        const float v6 = bf16bits_to_f32(S2[((size_t)c6 << 6) + lane]);
        const float v7 = bf16bits_to_f32(S2[((size_t)c7 << 6) + lane]);
        a0 += v0 + v4; a1 += v1 + v5; a2 += v2 + v6; a3 += v3 + v7;
    }
    for (; j < n; ++j) {
        const unsigned int d = cpd[j >> 1];
        const int c = (int)((j & 1) ? (d >> 16) : (d & 0xFFFFu)) + addB;
        a0 += bf16bits_to_f32(S2[((size_t)c << 6) + lane]);
    }

    return x0 + (s1 + s2) * rdv + dv * ((a0 + a1) + (a2 + a3));
}

__global__ __launch_bounds__(256) void out_kernel(
    const float* __restrict__ Gu, const float* __restrict__ Fp,
    const ushort_t* __restrict__ S1, const ushort_t* __restrict__ S2,
    const int* __restrict__ cnt, const ushort_t* __restrict__ col,
    const float* __restrict__ dinv,
    const int* __restrict__ uidx, const int* __restrict__ iidx,
    float* __restrict__ out, int B)
{
    const int wid = __builtin_amdgcn_readfirstlane(
        (int)((blockIdx.x * blockDim.x + threadIdx.x) >> 6));
    const int lane = threadIdx.x & 63;
    if (wid >= B) return;
    const int u  = uidx[wid];
    const int rI = NU + iidx[wid];

    const float au = row_acc(u,  Gu[((size_t)u  << 6) + lane], lane,
                             S1, S2, cnt, col, dinv);
    const float ai = row_acc(rI, Fp[((size_t)rI << 6) + lane], lane,
                             S1, S2, cnt, col, dinv);
    float p = au * ai;
    #pragma unroll
    for (int m = 32; m >= 1; m >>= 1) p += __shfl_xor(p, m);
    if (lane == 0) out[wid] = p * (1.0f / 16.0f);
}

extern "C" void kernel_launch(void* const* d_in, const int* in_sizes, int n_in,
                              void* d_out, int out_size, void* d_ws, size_t ws_size,
                              hipStream_t stream)
{
    const float* Gu = (const float*)d_in[0];
    const float* F0 = (const float*)d_in[1];
    const float* F1 = (const float*)d_in[2];
    const float* W  = (const float*)d_in[3];
    const float* pb = (const float*)d_in[4];
    const int* edge = (const int*)d_in[5];
    const int* uidx = (const int*)d_in[6];
    const int* iidx = (const int*)d_in[7];
    const int E  = in_sizes[5] / 2;      // 2,000,000 directed edges
    const int E2 = E / 2;                // 1,000,000 mirrored pairs
    const int B = in_sizes[6];           // 4096
    const int* srcp = edge;              // first E2: user ids
    const int* dstp = edge + E;          // first E2: item ids (+NU)

    const size_t XE = (size_t)NN * KDIM;
    float*    Fp    = (float*)d_ws;                        // XE f32 (items)
    ushort_t* curA  = (ushort_t*)(Fp + XE);                // XE bf16
    ushort_t* curB  = curA + XE;                           // XE bf16
    float*    dinv  = (float*)(curB + XE);                 // NN
    int*      cnt   = (int*)(dinv + NN);                   // NN
    int*      bcur  = cnt + NN;                            // NB
    short*    WTh   = (short*)(bcur + NB);                 // 64*896
    short*    WTl   = WTh + (size_t)KDIM * DD;             // 64*896
    ushort_t* col   = (ushort_t*)(WTl + (size_t)KDIM * DD);
    unsigned int* ents = (unsigned int*)col;               // aliased region

    // build: partition -> bucket-local ELL (emits cnt, dinv)
    (void)hipMemsetAsync(bcur, 0, NB * sizeof(int), stream);
    part_kernel<<<(E2 + CHUNK_PAIRS - 1) / CHUNK_PAIRS, 256, 0, stream>>>(
        srcp, dstp, bcur, ents, E2);
    toELL_kernel<<<NB, 256, 0, stream>>>(bcur, ents, col, cnt, dinv);

    // W -> transposed bf16 hi/lo
    wtcvt_kernel<<<(DD * KDIM + 255) / 256, 256, 0, stream>>>(W, WTh, WTl);

    // S0: curA = bf16(dinv .* x0)  (x0 = [Gu; Fproj]; Fp keeps item x0 in f32)
    userinit_kernel<<<(NU * KDIM / 4 + 255) / 256, 256, 0, stream>>>(
        Gu, dinv, curA);
    proj_kernel<<<(NI + 63) / 64, 256, 0, stream>>>(F0, F1, WTh, WTl, pb,
                                                    dinv, Fp, curA);

    // layers 1-2 (phase-split, 2 rows per wave); S1 = curB, S2 = curA
    const int gridU = (NU / 2 * 64 + 255) / 256;   // 6250
    const int gridI = (NI / 2 * 64 + 255) / 256;   // 3750
    pull_kernel<<<gridU, 256, 0, stream>>>(curA, curB, cnt, col, dinv, 0,  NU / 2);
    pull_kernel<<<gridI, 256, 0, stream>>>(curA, curB, cnt, col, dinv, NU, NI / 2);
    pull_kernel<<<gridU, 256, 0, stream>>>(curB, curA, cnt, col, dinv, 0,  NU / 2);
    pull_kernel<<<gridI, 256, 0, stream>>>(curB, curA, cnt, col, dinv, NU, NI / 2);

    // out: layer-3 at sampled rows only + mean + dot
    out_kernel<<<(int)(((size_t)B * 64 + 255) / 256), 256, 0, stream>>>(
        Gu, Fp, curB, curA, cnt, col, dinv, uidx, iidx, (float*)d_out, B);
}

// Round 20
// 165.780 us; speedup vs baseline: 1.0757x; 1.0695x over previous
//
#include <hip/hip_runtime.h>
#include <hip/hip_bf16.h>

#define NU 50000
#define NI 30000
#define NN 80000     // NU + NI
#define KDIM 64
#define DD0 768
#define DD1 128
#define DD 896       // DD0 + DD1 = 14 chunks of 64

#define BROWS 128            // dst rows per bucket
#define NB (NN / BROWS)      // 625 buckets
#define CAPB 5120            // entries per bucket region
#define CAP 96               // uniform ELL capacity per row (u16 slots)
#define REGION_BYTES 24576   // per-bucket region
#define ENTS_STRIDE (REGION_BYTES / 4)
#define CHUNK_PAIRS 4096

typedef __attribute__((ext_vector_type(8))) short short8v;
typedef __attribute__((ext_vector_type(4))) short short4v;
typedef __attribute__((ext_vector_type(4))) float float4v;
typedef unsigned short ushort_t;

struct bf16pair { short hi, lo; };

__device__ inline bf16pair f32_split_bf16(float v) {
    __hip_bfloat16 h = __float2bfloat16(v);
    float hf = __bfloat162float(h);
    __hip_bfloat16 l = __float2bfloat16(v - hf);
    bf16pair p;
    p.hi = *reinterpret_cast<short*>(&h);
    p.lo = *reinterpret_cast<short*>(&l);
    return p;
}

__device__ inline float bf16bits_to_f32(ushort_t u) {
    return __uint_as_float(((unsigned int)u) << 16);
}

__device__ inline ushort_t f32_to_bf16_rne(float f) {
    unsigned int u = __float_as_uint(f);
    unsigned int r = (u + 0x7FFFu + ((u >> 16) & 1u)) >> 16;
    return (ushort_t)r;
}

// ---------------------------------------------------------------------------
// W -> transposed bf16 hi/lo:  WTh/WTl[col][k]
// ---------------------------------------------------------------------------
__global__ void wtcvt_kernel(const float* __restrict__ W,
                             short* __restrict__ WTh, short* __restrict__ WTl)
{
    const int i = blockIdx.x * 256 + threadIdx.x;   // over DD*KDIM
    if (i < DD * KDIM) {
        const int k = i >> 6, col = i & 63;
        const bf16pair p = f32_split_bf16(W[i]);
        WTh[col * DD + k] = p.hi;
        WTl[col * DD + k] = p.lo;
    }
}

// ---------------------------------------------------------------------------
// 1) proj via bf16x2-split MFMA — R14/R17/R19 PROVEN best (55.6 us, VGPR 56):
// 64-row tile, 4 waves, LDS staging, 1-deep register prefetch. Disproven:
// 16-row (R11), LDS-free (R12), reg-dbuf (R13), 32-row (R15), split-K (R16),
// 2-deep prefetch (R18). The compiler's vmcnt(0) drain at each barrier sets
// this structure's HIP-source floor.
// Writes f32 item rows into Fp, bf16 dinv-scaled rows into curS.
// ---------------------------------------------------------------------------
__global__ __launch_bounds__(256) void proj_kernel(
    const float* __restrict__ F0, const float* __restrict__ F1,
    const short* __restrict__ WTh, const short* __restrict__ WTl,
    const float* __restrict__ b, const float* __restrict__ dinv,
    float* __restrict__ Fp, ushort_t* __restrict__ curS)
{
    __shared__ short Ah[64][72];
    __shared__ short Al[64][72];
    __shared__ short Bh[64][72];
    __shared__ short Bl[64][72];

    const int tid  = threadIdx.x;
    const int wv   = tid >> 6;      // wave 0..3
    const int lane = tid & 63;
    const int lr   = lane & 15;     // frag row/col
    const int grp  = lane >> 4;     // frag k-group
    const int rowBase = blockIdx.x * 64;

    const int aR[4] = { (0*256+tid) >> 4, (1*256+tid) >> 4,
                        (2*256+tid) >> 4, (3*256+tid) >> 4 };
    const int aK    = (tid & 15) * 4;
    const int bCol[2] = { (0*256+tid) >> 3, (1*256+tid) >> 3 };
    const int bK      = (tid & 7) * 8;

    float4   pA[4];
    short8v  pBh[2], pBl[2];

    auto loadChunk = [&](int c) {
        #pragma unroll
        for (int rep = 0; rep < 4; ++rep) {
            const int r = rowBase + aR[rep];
            float4 v = make_float4(0.f, 0.f, 0.f, 0.f);
            if (r < NI) {
                if (c < 12)
                    v = *(const float4*)&F0[(size_t)r * DD0 + c * 64 + aK];
                else
                    v = *(const float4*)&F1[(size_t)r * DD1 + (c - 12) * 64 + aK];
            }
            pA[rep] = v;
        }
        #pragma unroll
        for (int rep = 0; rep < 2; ++rep) {
            pBh[rep] = *(const short8v*)&WTh[(size_t)bCol[rep] * DD + c * 64 + bK];
            pBl[rep] = *(const short8v*)&WTl[(size_t)bCol[rep] * DD + c * 64 + bK];
        }
    };

    float4v acc[4] = {};

    loadChunk(0);
    for (int c = 0; c < 14; ++c) {
        #pragma unroll
        for (int rep = 0; rep < 4; ++rep) {
            const float4 v = pA[rep];
            const bf16pair p0 = f32_split_bf16(v.x);
            const bf16pair p1 = f32_split_bf16(v.y);
            const bf16pair p2 = f32_split_bf16(v.z);
            const bf16pair p3 = f32_split_bf16(v.w);
            short4v h4, l4;
            h4[0] = p0.hi; h4[1] = p1.hi; h4[2] = p2.hi; h4[3] = p3.hi;
            l4[0] = p0.lo; l4[1] = p1.lo; l4[2] = p2.lo; l4[3] = p3.lo;
            *(short4v*)&Ah[aR[rep]][aK] = h4;
            *(short4v*)&Al[aR[rep]][aK] = l4;
        }
        #pragma unroll
        for (int rep = 0; rep < 2; ++rep) {
            *(short8v*)&Bh[bCol[rep]][bK] = pBh[rep];
            *(short8v*)&Bl[bCol[rep]][bK] = pBl[rep];
        }
        if (c < 13) loadChunk(c + 1);   // in flight across MFMA phase
        __syncthreads();

        #pragma unroll
        for (int ks = 0; ks < 2; ++ks) {
            const int ko = ks * 32 + grp * 8;
            const short8v ah = *(const short8v*)&Ah[wv * 16 + lr][ko];
            const short8v al = *(const short8v*)&Al[wv * 16 + lr][ko];
            #pragma unroll
            for (int nt = 0; nt < 4; ++nt) {
                const short8v bh = *(const short8v*)&Bh[nt * 16 + lr][ko];
                const short8v bl = *(const short8v*)&Bl[nt * 16 + lr][ko];
                acc[nt] = __builtin_amdgcn_mfma_f32_16x16x32_bf16(ah, bh, acc[nt], 0, 0, 0);
                acc[nt] = __builtin_amdgcn_mfma_f32_16x16x32_bf16(ah, bl, acc[nt], 0, 0, 0);
                acc[nt] = __builtin_amdgcn_mfma_f32_16x16x32_bf16(al, bh, acc[nt], 0, 0, 0);
            }
        }
        __syncthreads();
    }

    float bias[4];
    #pragma unroll
    for (int nt = 0; nt < 4; ++nt) bias[nt] = b[nt * 16 + lr];

    float y[4][4];
    float ssp[4];
    #pragma unroll
    for (int i = 0; i < 4; ++i) {
        ssp[i] = 0.f;
        #pragma unroll
        for (int nt = 0; nt < 4; ++nt) {
            y[nt][i] = acc[nt][i] + bias[nt];
            ssp[i] += y[nt][i] * y[nt][i];
        }
    }
    #pragma unroll
    for (int i = 0; i < 4; ++i) {
        float ss = ssp[i];
        ss += __shfl_xor(ss, 1);
        ss += __shfl_xor(ss, 2);
        ss += __shfl_xor(ss, 4);
        ss += __shfl_xor(ss, 8);
        const int r = rowBase + wv * 16 + 4 * grp + i;
        if (r < NI) {
            const float inv = 1.0f / fmaxf(sqrtf(ss), 1e-12f);
            const float dv  = dinv[NU + r];
            #pragma unroll
            for (int nt = 0; nt < 4; ++nt) {
                const float o = y[nt][i] * inv;
                Fp[(size_t)(NU + r) * KDIM + nt * 16 + lr] = o;
                curS[(size_t)(NU + r) * KDIM + nt * 16 + lr] = f32_to_bf16_rne(o * dv);
            }
        }
    }
}

// user rows: curS = bf16(Gu * dinv[row])
__global__ void userinit_kernel(const float* __restrict__ Gu,
                                const float* __restrict__ dinv,
                                ushort_t* __restrict__ curS)
{
    const int i = blockIdx.x * blockDim.x + threadIdx.x;  // float4 index
    if (i < NU * KDIM / 4) {
        const int row = i >> 4;
        const float dv = dinv[row];
        const float4 g = ((const float4*)Gu)[i];
        short4v s;
        s[0] = (short)f32_to_bf16_rne(g.x * dv);
        s[1] = (short)f32_to_bf16_rne(g.y * dv);
        s[2] = (short)f32_to_bf16_rne(g.z * dv);
        s[3] = (short)f32_to_bf16_rne(g.w * dv);
        *(short4v*)&curS[(size_t)i * 4] = s;
    }
}

// ---------------------------------------------------------------------------
// Partition: bucket 2M directed entries by dst>>7 (R7-proven).
// ---------------------------------------------------------------------------
__global__ __launch_bounds__(256) void part_kernel(
    const int* __restrict__ src, const int* __restrict__ dst,
    int* __restrict__ bcur, unsigned int* __restrict__ ents, int E2)
{
    __shared__ int bcntL[NB];
    __shared__ int bposL[NB];
    const int tid = threadIdx.x;
    const int pairBase = blockIdx.x * CHUNK_PAIRS;

    for (int i = tid; i < NB; i += 256) bcntL[i] = 0;
    __syncthreads();

    #pragma unroll
    for (int it = 0; it < CHUNK_PAIRS / 256; ++it) {
        const int p = pairBase + it * 256 + tid;
        if (p < E2) {
            const int u  = src[p];
            const int iF = dst[p];
            atomicAdd(&bcntL[iF >> 7], 1);
            atomicAdd(&bcntL[u  >> 7], 1);
        }
    }
    __syncthreads();

    for (int bkt = tid; bkt < NB; bkt += 256) {
        const int c = bcntL[bkt];
        bposL[bkt] = (c > 0) ? atomicAdd(&bcur[bkt], c) : 0;
        bcntL[bkt] = 0;
    }
    __syncthreads();

    #pragma unroll
    for (int it = 0; it < CHUNK_PAIRS / 256; ++it) {
        const int p = pairBase + it * 256 + tid;
        if (p < E2) {
            const int u  = src[p];
            const int iF = dst[p];
            {
                const int bkt = iF >> 7;
                const int k = bposL[bkt] + atomicAdd(&bcntL[bkt], 1);
                if (k < CAPB)
                    ents[(size_t)bkt * ENTS_STRIDE + k] =
                        ((unsigned int)(iF & 127) << 16) | (unsigned int)u;
            }
            {
                const int bkt = u >> 7;
                const int k = bposL[bkt] + atomicAdd(&bcntL[bkt], 1);
                if (k < CAPB)
                    ents[(size_t)bkt * ENTS_STRIDE + k] =
                        ((unsigned int)(u & 127) << 16) | (unsigned int)(iF - NU);
            }
        }
    }
}

// ---------------------------------------------------------------------------
// toELL: stage bucket entries in LDS, place into u16 ELL [row][CAP]; emits
// cnt + dinv. (ELL aliases the entry region; LDS staging makes that safe.)
// ---------------------------------------------------------------------------
__global__ __launch_bounds__(256) void toELL_kernel(
    const int* __restrict__ bcur, unsigned int* __restrict__ ents,
    ushort_t* __restrict__ col,
    int* __restrict__ cnt, float* __restrict__ dinv)
{
    __shared__ unsigned int eL[CAPB];
    __shared__ int curL[BROWS];
    const int bkt = blockIdx.x;
    const int tid = threadIdx.x;

    int n = bcur[bkt]; n = (n < CAPB) ? n : CAPB;
    const unsigned int* ep = ents + (size_t)bkt * ENTS_STRIDE;

    for (int j = tid; j < n; j += 256) eL[j] = ep[j];
    if (tid < BROWS) curL[tid] = 0;
    __syncthreads();

    const size_t rowB = (size_t)bkt * BROWS;
    for (int j = tid; j < n; j += 256) {
        const unsigned int e = eL[j];
        const int dl = (int)(e >> 16);
        const int slot = atomicAdd(&curL[dl], 1);
        if (slot < CAP)
            col[(rowB + dl) * CAP + slot] = (ushort_t)(e & 0xFFFFu);
    }
    __syncthreads();

    if (tid < BROWS) {
        int c = curL[tid];
        c = (c < CAP) ? c : CAP;
        const size_t row = rowB + tid;
        cnt[row]  = c;
        dinv[row] = (c > 0) ? rsqrtf((float)c) : 0.0f;
    }
}

// ---------------------------------------------------------------------------
// 3) pull, two-rows-per-wave dword gathers (R18-proven), single full-range
// launch per layer: NU is even so a pair never straddles the user/item
// boundary -> addB stays wave-uniform. (Phase-split measured neutral on
// locality; merging saves 2 serial dispatches per layer.)
//    nxtS[row] = bf16( dinv^2 * sum_j curS[col_j] ).
// ---------------------------------------------------------------------------
__global__ __launch_bounds__(256) void pull_kernel(
    const ushort_t* __restrict__ curS, ushort_t* __restrict__ nxtS,
    const int* __restrict__ cnt,
    const ushort_t* __restrict__ col,
    const float* __restrict__ dinv,
    int nPairs)
{
    const int pr = __builtin_amdgcn_readfirstlane(
        (int)((blockIdx.x * blockDim.x + threadIdx.x) >> 6));
    const int lane = threadIdx.x & 63;
    const int sub  = lane & 31;     // dword index within the 128 B row
    const int h    = lane >> 5;     // which row of the pair
    if (pr >= nPairs) return;
    const int row0 = pr * 2;
    const int rowH = row0 + h;
    const int addB = (row0 < NU) ? NU : 0;   // wave-uniform (NU even)
    const int n0 = cnt[row0];
    const int n1 = cnt[row0 + 1];
    const int nH   = h ? n1 : n0;
    const int nMin = (n0 < n1) ? n0 : n1;
    const int nMax = (n0 < n1) ? n1 : n0;
    const unsigned int* cp0 = (const unsigned int*)(col + (size_t)row0 * CAP);
    const unsigned int* cp1 = (const unsigned int*)(col + ((size_t)row0 + 1) * CAP);

    float aLo0 = 0.f, aLo1 = 0.f, aHi0 = 0.f, aHi1 = 0.f;
    int j = 0;
    for (; j + 8 <= nMin; j += 8) {
        const uint4 D0 = *(const uint4*)(cp0 + (j >> 1));
        const uint4 D1 = *(const uint4*)(cp1 + (j >> 1));
        const unsigned int dx = h ? D1.x : D0.x;
        const unsigned int dy = h ? D1.y : D0.y;
        const unsigned int dz = h ? D1.z : D0.z;
        const unsigned int dw = h ? D1.w : D0.w;
        const int c0 = (int)(dx & 0xFFFFu) + addB;
        const int c1 = (int)(dx >> 16)     + addB;
        const int c2 = (int)(dy & 0xFFFFu) + addB;
        const int c3 = (int)(dy >> 16)     + addB;
        const int c4 = (int)(dz & 0xFFFFu) + addB;
        const int c5 = (int)(dz >> 16)     + addB;
        const int c6 = (int)(dw & 0xFFFFu) + addB;
        const int c7 = (int)(dw >> 16)     + addB;
        const unsigned int v0 = *(const unsigned int*)&curS[((size_t)c0 << 6) + sub * 2];
        const unsigned int v1 = *(const unsigned int*)&curS[((size_t)c1 << 6) + sub * 2];
        const unsigned int v2 = *(const unsigned int*)&curS[((size_t)c2 << 6) + sub * 2];
        const unsigned int v3 = *(const unsigned int*)&curS[((size_t)c3 << 6) + sub * 2];
        const unsigned int v4 = *(const unsigned int*)&curS[((size_t)c4 << 6) + sub * 2];
        const unsigned int v5 = *(const unsigned int*)&curS[((size_t)c5 << 6) + sub * 2];
        const unsigned int v6 = *(const unsigned int*)&curS[((size_t)c6 << 6) + sub * 2];
        const unsigned int v7 = *(const unsigned int*)&curS[((size_t)c7 << 6) + sub * 2];
        aLo0 += __uint_as_float(v0 << 16) + __uint_as_float(v2 << 16);
        aLo1 += __uint_as_float(v1 << 16) + __uint_as_float(v3 << 16);
        aHi0 += __uint_as_float(v0 & 0xFFFF0000u) + __uint_as_float(v2 & 0xFFFF0000u);
        aHi1 += __uint_as_float(v1 & 0xFFFF0000u) + __uint_as_float(v3 & 0xFFFF0000u);
        aLo0 += __uint_as_float(v4 << 16) + __uint_as_float(v6 << 16);
        aLo1 += __uint_as_float(v5 << 16) + __uint_as_float(v7 << 16);
        aHi0 += __uint_as_float(v4 & 0xFFFF0000u) + __uint_as_float(v6 & 0xFFFF0000u);
        aHi1 += __uint_as_float(v5 & 0xFFFF0000u) + __uint_as_float(v7 & 0xFFFF0000u);
    }
    for (; j < nMax; j += 2) {       // tail: per-half predication
        const unsigned int d0 = cp0[j >> 1];
        const unsigned int d1 = cp1[j >> 1];
        const unsigned int d  = h ? d1 : d0;
        if (j < nH) {
            const int c = (int)(d & 0xFFFFu) + addB;
            const unsigned int v = *(const unsigned int*)&curS[((size_t)c << 6) + sub * 2];
            aLo0 += __uint_as_float(v << 16);
            aHi0 += __uint_as_float(v & 0xFFFF0000u);
        }
        if (j + 1 < nH) {
            const int c = (int)(d >> 16) + addB;
            const unsigned int v = *(const unsigned int*)&curS[((size_t)c << 6) + sub * 2];
            aLo1 += __uint_as_float(v << 16);
            aHi1 += __uint_as_float(v & 0xFFFF0000u);
        }
    }

    const float dv = dinv[rowH];
    const float f = dv * dv;
    const unsigned int w = (unsigned int)f32_to_bf16_rne((aLo0 + aLo1) * f)
                         | ((unsigned int)f32_to_bf16_rne((aHi0 + aHi1) * f) << 16);
    ((unsigned int*)&nxtS[(size_t)rowH << 6])[sub] = w;
}

// ---------------------------------------------------------------------------
// 4) out: acc_r = x0_r + (S1_r + S2_r)/dinv_r + dinv_r * sum_j S2[col_j(r)]
//    xui[b] = (1/16) * dot(acc_u, acc_i).  Layer-3 evaluated only here.
// ---------------------------------------------------------------------------
__device__ inline float row_acc(int row, float x0, int lane,
                                const ushort_t* __restrict__ S1,
                                const ushort_t* __restrict__ S2,
                                const int* __restrict__ cnt,
                                const ushort_t* __restrict__ col,
                                const float* __restrict__ dinv)
{
    const float dv  = dinv[row];
    const float rdv = (dv > 0.f) ? 1.0f / dv : 0.0f;
    const float s1 = bf16bits_to_f32(S1[((size_t)row << 6) + lane]);
    const float s2 = bf16bits_to_f32(S2[((size_t)row << 6) + lane]);

    const unsigned int* cpd = (const unsigned int*)(col + (size_t)row * CAP);
    const int addB = (row < NU) ? NU : 0;
    const int n = cnt[row];
    float a0 = 0.f, a1 = 0.f, a2 = 0.f, a3 = 0.f;
    int j = 0;
    for (; j + 8 <= n; j += 8) {
        const uint4 cc = *(const uint4*)(cpd + (j >> 1));
        const int c0 = (int)(cc.x & 0xFFFFu) + addB;
        const int c1 = (int)(cc.x >> 16)     + addB;
        const int c2 = (int)(cc.y & 0xFFFFu) + addB;
        const int c3 = (int)(cc.y >> 16)     + addB;
        const int c4 = (int)(cc.z & 0xFFFFu) + addB;
        const int c5 = (int)(cc.z >> 16)     + addB;
        const int c6 = (int)(cc.w & 0xFFFFu) + addB;
        const int c7 = (int)(cc.w >> 16)     + addB;
        const float v0 = bf16bits_to_f32(S2[((size_t)c0 << 6) + lane]);
        const float v1 = bf16bits_to_f32(S2[((size_t)c1 << 6) + lane]);
        const float v2 = bf16bits_to_f32(S2[((size_t)c2 << 6) + lane]);
        const float v3 = bf16bits_to_f32(S2[((size_t)c3 << 6) + lane]);
        const float v4 = bf16bits_to_f32(S2[((size_t)c4 << 6) + lane]);
        const float v5 = bf16bits_to_f32(S2[((size_t)c5 << 6) + lane]);
        const float v6 = bf16bits_to_f32(S2[((size_t)c6 << 6) + lane]);
        const float v7 = bf16bits_to_f32(S2[((size_t)c7 << 6) + lane]);
        a0 += v0 + v4; a1 += v1 + v5; a2 += v2 + v6; a3 += v3 + v7;
    }
    for (; j < n; ++j) {
        const unsigned int d = cpd[j >> 1];
        const int c = (int)((j & 1) ? (d >> 16) : (d & 0xFFFFu)) + addB;
        a0 += bf16bits_to_f32(S2[((size_t)c << 6) + lane]);
    }

    return x0 + (s1 + s2) * rdv + dv * ((a0 + a1) + (a2 + a3));
}

__global__ __launch_bounds__(256) void out_kernel(
    const float* __restrict__ Gu, const float* __restrict__ Fp,
    const ushort_t* __restrict__ S1, const ushort_t* __restrict__ S2,
    const int* __restrict__ cnt, const ushort_t* __restrict__ col,
    const float* __restrict__ dinv,
    const int* __restrict__ uidx, const int* __restrict__ iidx,
    float* __restrict__ out, int B)
{
    const int wid = __builtin_amdgcn_readfirstlane(
        (int)((blockIdx.x * blockDim.x + threadIdx.x) >> 6));
    const int lane = threadIdx.x & 63;
    if (wid >= B) return;
    const int u  = uidx[wid];
    const int rI = NU + iidx[wid];

    const float au = row_acc(u,  Gu[((size_t)u  << 6) + lane], lane,
                             S1, S2, cnt, col, dinv);
    const float ai = row_acc(rI, Fp[((size_t)rI << 6) + lane], lane,
                             S1, S2, cnt, col, dinv);
    float p = au * ai;
    #pragma unroll
    for (int m = 32; m >= 1; m >>= 1) p += __shfl_xor(p, m);
    if (lane == 0) out[wid] = p * (1.0f / 16.0f);
}

extern "C" void kernel_launch(void* const* d_in, const int* in_sizes, int n_in,
                              void* d_out, int out_size, void* d_ws, size_t ws_size,
                              hipStream_t stream)
{
    const float* Gu = (const float*)d_in[0];
    const float* F0 = (const float*)d_in[1];
    const float* F1 = (const float*)d_in[2];
    const float* W  = (const float*)d_in[3];
    const float* pb = (const float*)d_in[4];
    const int* edge = (const int*)d_in[5];
    const int* uidx = (const int*)d_in[6];
    const int* iidx = (const int*)d_in[7];
    const int E  = in_sizes[5] / 2;      // 2,000,000 directed edges
    const int E2 = E / 2;                // 1,000,000 mirrored pairs
    const int B = in_sizes[6];           // 4096
    const int* srcp = edge;              // first E2: user ids
    const int* dstp = edge + E;          // first E2: item ids (+NU)

    const size_t XE = (size_t)NN * KDIM;
    float*    Fp    = (float*)d_ws;                        // XE f32 (items)
    ushort_t* curA  = (ushort_t*)(Fp + XE);                // XE bf16
    ushort_t* curB  = curA + XE;                           // XE bf16
    float*    dinv  = (float*)(curB + XE);                 // NN
    int*      cnt   = (int*)(dinv + NN);                   // NN
    int*      bcur  = cnt + NN;                            // NB
    short*    WTh   = (short*)(bcur + NB);                 // 64*896
    short*    WTl   = WTh + (size_t)KDIM * DD;             // 64*896
    ushort_t* col   = (ushort_t*)(WTl + (size_t)KDIM * DD);
    unsigned int* ents = (unsigned int*)col;               // aliased region

    // build: partition -> bucket-local ELL (emits cnt, dinv)
    (void)hipMemsetAsync(bcur, 0, NB * sizeof(int), stream);
    part_kernel<<<(E2 + CHUNK_PAIRS - 1) / CHUNK_PAIRS, 256, 0, stream>>>(
        srcp, dstp, bcur, ents, E2);
    toELL_kernel<<<NB, 256, 0, stream>>>(bcur, ents, col, cnt, dinv);

    // W -> transposed bf16 hi/lo
    wtcvt_kernel<<<(DD * KDIM + 255) / 256, 256, 0, stream>>>(W, WTh, WTl);

    // S0: curA = bf16(dinv .* x0)  (x0 = [Gu; Fproj]; Fp keeps item x0 in f32)
    userinit_kernel<<<(NU * KDIM / 4 + 255) / 256, 256, 0, stream>>>(
        Gu, dinv, curA);
    proj_kernel<<<(NI + 63) / 64, 256, 0, stream>>>(F0, F1, WTh, WTl, pb,
                                                    dinv, Fp, curA);

    // layers 1-2 (single full-range launch per layer; 2 rows per wave)
    const int gridP = (NN / 2 * 64 + 255) / 256;   // 10000
    pull_kernel<<<gridP, 256, 0, stream>>>(curA, curB, cnt, col, dinv, NN / 2);
    pull_kernel<<<gridP, 256, 0, stream>>>(curB, curA, cnt, col, dinv, NN / 2);

    // out: layer-3 at sampled rows only + mean + dot
    out_kernel<<<(int)(((size_t)B * 64 + 255) / 256), 256, 0, stream>>>(
        Gu, Fp, curB, curA, cnt, col, dinv, uidx, iidx, (float*)d_out, B);
}